// Round 8
// baseline (345.544 us; speedup 1.0000x reference)
//
#include <hip/hip_runtime.h>

typedef __attribute__((ext_vector_type(8))) short   short8;
typedef __attribute__((ext_vector_type(8))) __bf16  bf16x8;
typedef __attribute__((ext_vector_type(4))) __bf16  bf16x4;
typedef __attribute__((ext_vector_type(4))) float   f32x4;
typedef __attribute__((ext_vector_type(4))) unsigned short ushort4v;

#define NSTEPS 49

static __device__ __forceinline__ short8 as_s8(bf16x8 v) {
    return __builtin_bit_cast(short8, v);
}
static __device__ __forceinline__ bf16x4 pack4(f32x4 v) {
    bf16x4 b;
    b[0] = (__bf16)v[0]; b[1] = (__bf16)v[1];
    b[2] = (__bf16)v[2]; b[3] = (__bf16)v[3];
    return b;
}

#define MFMA(A, B, C) __builtin_amdgcn_mfma_f32_16x16x32_bf16((A), (B), (C), 0, 0, 0)

// Third L1 K-slice: slot (q=0,j=0) carries t, (q=0,j=1) carries 1.0 (bias col).
#define BUILD_XT(TV)                                                         \
    {                                                                        \
        bf16x8 v_;                                                           \
        _Pragma("unroll") for (int j_ = 0; j_ < 8; ++j_) v_[j_] = (__bf16)0.f; \
        if (q == 0) { v_[0] = (__bf16)(TV); v_[1] = (__bf16)1.0f; }          \
        xt = as_s8(v_);                                                      \
    }

#define RELU_PACK(AA, AB, OUT)                                               \
    {                                                                        \
        bf16x8 v_;                                                           \
        v_[0]=(__bf16)fmaxf((AA)[0],0.f); v_[1]=(__bf16)fmaxf((AA)[1],0.f);  \
        v_[2]=(__bf16)fmaxf((AA)[2],0.f); v_[3]=(__bf16)fmaxf((AA)[3],0.f);  \
        v_[4]=(__bf16)fmaxf((AB)[0],0.f); v_[5]=(__bf16)fmaxf((AB)[1],0.f);  \
        v_[6]=(__bf16)fmaxf((AB)[2],0.f); v_[7]=(__bf16)fmaxf((AB)[3],0.f);  \
        OUT = as_s8(v_);                                                     \
    }

// One Tsit5 stage for TWO independent 16-row systems (A,B), 4-wave
// cooperative. A's and B's phase work is fully independent: B's ds_reads
// and MFMA chains execute under A's load latency and chain tails, and each
// barrier fences both systems (half the barrier cost per unit work vs R7).
// Weights register-resident; LDS only for activation slices ([slice][lane],
// 16B/lane, conflict-free reads). si = pre + h*kv with pre computed
// off-path after the previous stage's last barrier.
#define STAGE2(TN, HS)                                                       \
    {                                                                        \
        const f32x4 zz = {0.f, 0.f, 0.f, 0.f};                               \
        short8 xt; BUILD_XT(TN);                                             \
        /* ---- P1: L1 (si -> h), tiles 2w,2w+1, systems A+B ---- */         \
        short8 xs0A = *(const short8*)(&XSA[0][lane][0]);                    \
        short8 xs1A = *(const short8*)(&XSA[1][lane][0]);                    \
        short8 xs0B = *(const short8*)(&XSB[0][lane][0]);                    \
        short8 xs1B = *(const short8*)(&XSB[1][lane][0]);                    \
        f32x4 hAa = MFMA(wL1[0], xs0A, zz); hAa = MFMA(wL1[1], xs1A, hAa);   \
        hAa = MFMA(wL1[2], xt, hAa);                                         \
        f32x4 hAb = MFMA(wL1[3], xs0A, zz); hAb = MFMA(wL1[4], xs1A, hAb);   \
        hAb = MFMA(wL1[5], xt, hAb);                                         \
        f32x4 hBa = MFMA(wL1[0], xs0B, zz); hBa = MFMA(wL1[1], xs1B, hBa);   \
        hBa = MFMA(wL1[2], xt, hBa);                                         \
        f32x4 hBb = MFMA(wL1[3], xs0B, zz); hBb = MFMA(wL1[4], xs1B, hBb);   \
        hBb = MFMA(wL1[5], xt, hBb);                                         \
        short8 xhmA; RELU_PACK(hAa, hAb, xhmA);                              \
        short8 xhmB; RELU_PACK(hBa, hBb, xhmB);                              \
        *(short8*)(&XHA[w][lane][0]) = xhmA;                                 \
        *(short8*)(&XHB[w][lane][0]) = xhmB;                                 \
        __syncthreads();                                                     \
        /* ---- P2: L2 (h -> g) ---- */                                      \
        short8 xh0A = *(const short8*)(&XHA[0][lane][0]);                    \
        short8 xh1A = *(const short8*)(&XHA[1][lane][0]);                    \
        short8 xh2A = *(const short8*)(&XHA[2][lane][0]);                    \
        short8 xh3A = *(const short8*)(&XHA[3][lane][0]);                    \
        short8 xh0B = *(const short8*)(&XHB[0][lane][0]);                    \
        short8 xh1B = *(const short8*)(&XHB[1][lane][0]);                    \
        short8 xh2B = *(const short8*)(&XHB[2][lane][0]);                    \
        short8 xh3B = *(const short8*)(&XHB[3][lane][0]);                    \
        f32x4 gAa = MFMA(wL2[0], xh0A, bL2v[0]); gAa = MFMA(wL2[1], xh1A, gAa); \
        gAa = MFMA(wL2[2], xh2A, gAa);           gAa = MFMA(wL2[3], xh3A, gAa); \
        f32x4 gAb = MFMA(wL2[4], xh0A, bL2v[1]); gAb = MFMA(wL2[5], xh1A, gAb); \
        gAb = MFMA(wL2[6], xh2A, gAb);           gAb = MFMA(wL2[7], xh3A, gAb); \
        f32x4 gBa = MFMA(wL2[0], xh0B, bL2v[0]); gBa = MFMA(wL2[1], xh1B, gBa); \
        gBa = MFMA(wL2[2], xh2B, gBa);           gBa = MFMA(wL2[3], xh3B, gBa); \
        f32x4 gBb = MFMA(wL2[4], xh0B, bL2v[1]); gBb = MFMA(wL2[5], xh1B, gBb); \
        gBb = MFMA(wL2[6], xh2B, gBb);           gBb = MFMA(wL2[7], xh3B, gBb); \
        short8 xgmA; RELU_PACK(gAa, gAb, xgmA);                              \
        short8 xgmB; RELU_PACK(gBa, gBb, xgmB);                              \
        *(short8*)(&XGA[w][lane][0]) = xgmA;                                 \
        *(short8*)(&XGB[w][lane][0]) = xgmB;                                 \
        __syncthreads();                                                     \
        /* ---- P3: L3 (g -> kv); si = pre + h*kv ---- */                    \
        short8 xg0A = *(const short8*)(&XGA[0][lane][0]);                    \
        short8 xg1A = *(const short8*)(&XGA[1][lane][0]);                    \
        short8 xg2A = *(const short8*)(&XGA[2][lane][0]);                    \
        short8 xg3A = *(const short8*)(&XGA[3][lane][0]);                    \
        short8 xg0B = *(const short8*)(&XGB[0][lane][0]);                    \
        short8 xg1B = *(const short8*)(&XGB[1][lane][0]);                    \
        short8 xg2B = *(const short8*)(&XGB[2][lane][0]);                    \
        short8 xg3B = *(const short8*)(&XGB[3][lane][0]);                    \
        kvA = MFMA(wL3[0], xg0A, bL3v); kvA = MFMA(wL3[1], xg1A, kvA);       \
        kvA = MFMA(wL3[2], xg2A, kvA);  kvA = MFMA(wL3[3], xg3A, kvA);       \
        kvB = MFMA(wL3[0], xg0B, bL3v); kvB = MFMA(wL3[1], xg1B, kvB);       \
        kvB = MFMA(wL3[2], xg2B, kvB);  kvB = MFMA(wL3[3], xg3B, kvB);       \
        _Pragma("unroll")                                                    \
        for (int r_ = 0; r_ < 4; ++r_) {                                     \
            siA[r_] = preA[r_] + (HS) * kvA[r_];                             \
            siB[r_] = preB[r_] + (HS) * kvB[r_];                             \
        }                                                                    \
        *(ushort4v*)(&XSA[w >> 1][lane][4 * (w & 1)]) =                      \
            __builtin_bit_cast(ushort4v, pack4(siA));                       \
        *(ushort4v*)(&XSB[w >> 1][lane][4 * (w & 1)]) =                      \
            __builtin_bit_cast(ushort4v, pack4(siB));                       \
        __syncthreads();                                                     \
    }

// 4 waves per block own 32 batch rows as two independent 16-row systems.
// Wave w holds L1 tiles 2w,2w+1 (6 frags), L2 tiles 2w,2w+1 (8), L3 tile w
// (4) = 72 VGPRs of weights + both systems' ODE state (~48 regs). The A/B
// interleave fills the ds_read latency + MFMA-chain tails that left R7 at
// 9% MfmaUtil with 1 wave/SIMD; barriers amortize 2x.
extern "C" __global__ void __launch_bounds__(256, 1)
node_solve(const float* __restrict__ y0, const float* __restrict__ ts,
           const float* __restrict__ gw0, const float* __restrict__ gb0,
           const float* __restrict__ gw1, const float* __restrict__ gb1,
           const float* __restrict__ gw2, const float* __restrict__ gb2,
           float* __restrict__ out)
{
    __shared__ __align__(16) unsigned short XSA[2][64][8], XSB[2][64][8];
    __shared__ __align__(16) unsigned short XHA[4][64][8], XHB[4][64][8];
    __shared__ __align__(16) unsigned short XGA[4][64][8], XGB[4][64][8];

    const int tid  = threadIdx.x;
    const int w    = tid >> 6;      // wave 0..3
    const int lane = tid & 63;
    const int q    = lane >> 4;
    const int c    = lane & 15;
    const int row0 = blockIdx.x << 5;   // 32 rows/block

    // ---- weights -> K-permuted register A-frags (this wave's tiles only) ----
    // perm: k-position (ks, q, j) <- source column 32ks+16*(j>>2)+4q+(j&3)
    short8 wL1[6];   // tiles 2w,2w+1 x slices {y0-31, y32-63, [t,bias]}
    short8 wL2[8];   // tiles 2w,2w+1 x 4 k-slices
    short8 wL3[4];   // tile w x 4 k-slices
    f32x4  bL2v[2], bL3v;

    #pragma unroll
    for (int p = 0; p < 2; ++p) {
        const int t = 2 * w + p;
        const int n = 16 * t + c;
        const float* w0r = gw0 + n * 65 + 1;      // col 0 of gw0 is the t-weight
        #pragma unroll
        for (int ks = 0; ks < 2; ++ks) {
            bf16x8 v;
            #pragma unroll
            for (int j = 0; j < 8; ++j)
                v[j] = (__bf16)w0r[32*ks + 16*(j>>2) + 4*q + (j&3)];
            wL1[3*p + ks] = as_s8(v);
        }
        {
            bf16x8 v;
            #pragma unroll
            for (int j = 0; j < 8; ++j) v[j] = (__bf16)0.f;
            if (q == 0) { v[0] = (__bf16)gw0[n*65]; v[1] = (__bf16)gb0[n]; }
            wL1[3*p + 2] = as_s8(v);
        }
        const float* w1r = gw1 + n * 128;
        #pragma unroll
        for (int ks = 0; ks < 4; ++ks) {
            bf16x8 v;
            #pragma unroll
            for (int j = 0; j < 8; ++j)
                v[j] = (__bf16)w1r[32*ks + 16*(j>>2) + 4*q + (j&3)];
            wL2[4*p + ks] = as_s8(v);
        }
        bL2v[p] = *(const f32x4*)(gb1 + 16*t + 4*q);
    }
    {
        const int n = 16 * w + c;
        const float* w2r = gw2 + n * 128;
        #pragma unroll
        for (int ks = 0; ks < 4; ++ks) {
            bf16x8 v;
            #pragma unroll
            for (int j = 0; j < 8; ++j)
                v[j] = (__bf16)w2r[32*ks + 16*(j>>2) + 4*q + (j&3)];
            wL3[ks] = as_s8(v);
        }
        bL3v = *(const f32x4*)(gb2 + 16*w + 4*q);
    }

    // ---- ODE state: wave owns dims 16w+4q+r of rows row0+c (A), row0+16+c (B) ----
    f32x4 ynA = *(const f32x4*)(y0 + (size_t)(row0 + c)      * 64 + 16*w + 4*q);
    f32x4 ynB = *(const f32x4*)(y0 + (size_t)(row0 + 16 + c) * 64 + 16*w + 4*q);

    const float ts0 = ts[0];
    const float dtv = ts[1] - ts[0];

    // dt-scaled Tsit5: e = dt*b, h_s = dt*a_{s+1,s}, g_sj = dt*(a_sj - b_j)
    const float e1 = dtv * 0.09646076681806523f, e2 = dtv * 0.01f;
    const float e3 = dtv * 0.4798896504144996f,  e4 = dtv * 1.379008574103742f;
    const float e5 = dtv * -3.290069515436081f,  e6 = dtv * 2.324710524099774f;
    const float h0 = dtv * 0.161f;
    const float h1 = dtv * 0.335480655492357f;
    const float h2 = dtv * 4.3622954328695815f;
    const float h3 = dtv * -0.09249506636175525f;
    const float h4 = dtv * -0.028269050394068383f;
    const float g31 = dtv * (-0.008480655492356989f - 0.09646076681806523f);
    const float g41 = dtv * (2.8971530571054935f    - 0.09646076681806523f);
    const float g42 = dtv * (-6.359448489975075f    - 0.01f);
    const float g51 = dtv * (5.325864828439257f     - 0.09646076681806523f);
    const float g52 = dtv * (-11.748883564062828f   - 0.01f);
    const float g53 = dtv * (7.4955393428898365f    - 0.4798896504144996f);
    const float g61 = dtv * (5.86145544294642f      - 0.09646076681806523f);
    const float g62 = dtv * (-12.92096931784711f    - 0.01f);
    const float g63 = dtv * (8.159367898576159f     - 0.4798896504144996f);
    const float g64 = dtv * (-0.071584973281401f    - 1.379008574103742f);

    // ---- initial stage inputs si1 = y0 ----
    *(ushort4v*)(&XSA[w >> 1][lane][4 * (w & 1)]) =
        __builtin_bit_cast(ushort4v, pack4(ynA));
    *(ushort4v*)(&XSB[w >> 1][lane][4 * (w & 1)]) =
        __builtin_bit_cast(ushort4v, pack4(ynB));
    f32x4 preA = ynA, preB = ynB, siA, siB, kvA, kvB;
    __syncthreads();

    #pragma unroll 1
    for (int step = 0; step < NSTEPS; ++step) {
        const float t0s = ts0 + (float)step * dtv;
        bf16x4 kA0, kA1, kA2, kA3, kB0, kB1, kB2, kB3;

        // ---- stage 1 ----  (tails after barrier: register-only, overlap P1)
        STAGE2(t0s, h0)
        #pragma unroll
        for (int r = 0; r < 4; ++r) { ynA[r] += e1 * kvA[r]; ynB[r] += e1 * kvB[r]; }
        kA0 = pack4(kvA); kB0 = pack4(kvB);
        #pragma unroll
        for (int r = 0; r < 4; ++r) {
            preA[r] = ynA[r] + g31 * (float)kA0[r];
            preB[r] = ynB[r] + g31 * (float)kB0[r];
        }

        // ---- stage 2 ----
        STAGE2(t0s + 0.161f * dtv, h1)
        #pragma unroll
        for (int r = 0; r < 4; ++r) { ynA[r] += e2 * kvA[r]; ynB[r] += e2 * kvB[r]; }
        kA1 = pack4(kvA); kB1 = pack4(kvB);
        #pragma unroll
        for (int r = 0; r < 4; ++r) {
            preA[r] = ynA[r] + g41 * (float)kA0[r] + g42 * (float)kA1[r];
            preB[r] = ynB[r] + g41 * (float)kB0[r] + g42 * (float)kB1[r];
        }

        // ---- stage 3 ----
        STAGE2(t0s + 0.327f * dtv, h2)
        #pragma unroll
        for (int r = 0; r < 4; ++r) { ynA[r] += e3 * kvA[r]; ynB[r] += e3 * kvB[r]; }
        kA2 = pack4(kvA); kB2 = pack4(kvB);
        #pragma unroll
        for (int r = 0; r < 4; ++r) {
            preA[r] = ynA[r] + g51 * (float)kA0[r] + g52 * (float)kA1[r]
                    + g53 * (float)kA2[r];
            preB[r] = ynB[r] + g51 * (float)kB0[r] + g52 * (float)kB1[r]
                    + g53 * (float)kB2[r];
        }

        // ---- stage 4 ----
        STAGE2(t0s + 0.9f * dtv, h3)
        #pragma unroll
        for (int r = 0; r < 4; ++r) { ynA[r] += e4 * kvA[r]; ynB[r] += e4 * kvB[r]; }
        kA3 = pack4(kvA); kB3 = pack4(kvB);
        #pragma unroll
        for (int r = 0; r < 4; ++r) {
            preA[r] = ynA[r] + g61 * (float)kA0[r] + g62 * (float)kA1[r]
                    + g63 * (float)kA2[r] + g64 * (float)kA3[r];
            preB[r] = ynB[r] + g61 * (float)kB0[r] + g62 * (float)kB1[r]
                    + g63 * (float)kB2[r] + g64 * (float)kB3[r];
        }

        // ---- stage 5 ----
        STAGE2(t0s + 0.9800255409045097f * dtv, h4)
        #pragma unroll
        for (int r = 0; r < 4; ++r) {
            ynA[r] += e5 * kvA[r]; preA[r] = ynA[r];
            ynB[r] += e5 * kvB[r]; preB[r] = ynB[r];
        }

        // ---- stage 6: si = yn + e6*kv = new y (exact f32 carry) ----
        STAGE2(t0s + dtv, e6)
        #pragma unroll
        for (int r = 0; r < 4; ++r) {
            ynA[r] = siA[r]; preA[r] = siA[r];
            ynB[r] = siB[r]; preB[r] = siB[r];
        }
    }

    // ---- output ----
    *(f32x4*)(&out[(size_t)(row0 + c)      * 64 + 16*w + 4*q]) = ynA;
    *(f32x4*)(&out[(size_t)(row0 + 16 + c) * 64 + 16*w + 4*q]) = ynB;
}

extern "C" void kernel_launch(void* const* d_in, const int* in_sizes, int n_in,
                              void* d_out, int out_size, void* d_ws, size_t ws_size,
                              hipStream_t stream) {
    const float* y0 = (const float*)d_in[0];
    const float* ts = (const float*)d_in[1];
    const float* w0 = (const float*)d_in[2];
    const float* b0 = (const float*)d_in[3];
    const float* w1 = (const float*)d_in[4];
    const float* b1 = (const float*)d_in[5];
    const float* w2 = (const float*)d_in[6];
    const float* b2 = (const float*)d_in[7];
    float* out = (float*)d_out;

    node_solve<<<dim3(64), dim3(256), 0, stream>>>(y0, ts, w0, b0, w1, b1, w2, b2, out);
}

// Round 9
// 284.034 us; speedup vs baseline: 1.2166x; 1.2166x over previous
//
#include <hip/hip_runtime.h>

typedef __attribute__((ext_vector_type(8))) short   short8;
typedef __attribute__((ext_vector_type(8))) __bf16  bf16x8;
typedef __attribute__((ext_vector_type(4))) __bf16  bf16x4;
typedef __attribute__((ext_vector_type(4))) float   f32x4;
typedef __attribute__((ext_vector_type(4))) unsigned short ushort4v;

#define NSTEPS 49

static __device__ __forceinline__ short8 as_s8(bf16x8 v) {
    return __builtin_bit_cast(short8, v);
}
static __device__ __forceinline__ bf16x4 pack4(f32x4 v) {
    bf16x4 b;
    b[0] = (__bf16)v[0]; b[1] = (__bf16)v[1];
    b[2] = (__bf16)v[2]; b[3] = (__bf16)v[3];
    return b;
}

#define MFMA(A, B, C) __builtin_amdgcn_mfma_f32_16x16x32_bf16((A), (B), (C), 0, 0, 0)

// Third L1 K-slice: slot (q=0,j=0) carries t, (q=0,j=1) carries 1.0 (bias col).
#define BUILD_XT(TV)                                                         \
    {                                                                        \
        bf16x8 v_;                                                           \
        _Pragma("unroll") for (int j_ = 0; j_ < 8; ++j_) v_[j_] = (__bf16)0.f; \
        if (q == 0) { v_[0] = (__bf16)(TV); v_[1] = (__bf16)1.0f; }          \
        xt = as_s8(v_);                                                      \
    }

#define RELU_PACK(AA, AB, OUT)                                               \
    {                                                                        \
        bf16x8 v_;                                                           \
        v_[0]=(__bf16)fmaxf((AA)[0],0.f); v_[1]=(__bf16)fmaxf((AA)[1],0.f);  \
        v_[2]=(__bf16)fmaxf((AA)[2],0.f); v_[3]=(__bf16)fmaxf((AA)[3],0.f);  \
        v_[4]=(__bf16)fmaxf((AB)[0],0.f); v_[5]=(__bf16)fmaxf((AB)[1],0.f);  \
        v_[6]=(__bf16)fmaxf((AB)[2],0.f); v_[7]=(__bf16)fmaxf((AB)[3],0.f);  \
        OUT = as_s8(v_);                                                     \
    }

// One full Tsit5 stage — identical per-wave work to R7 (one system per wave).
// XSs/XHs/XGs point at this wave's system's LDS buffers.
#define STAGE(TN, HS)                                                        \
    {                                                                        \
        const f32x4 zz = {0.f, 0.f, 0.f, 0.f};                               \
        /* ---- P1: L1 (si -> h), tiles 2w, 2w+1 ---- */                     \
        short8 xs0 = *(const short8*)(&XSs[0][lane][0]);                     \
        short8 xs1 = *(const short8*)(&XSs[1][lane][0]);                     \
        short8 xt; BUILD_XT(TN);                                             \
        f32x4 aA = MFMA(wL1[0], xs0, zz); aA = MFMA(wL1[1], xs1, aA);        \
        aA = MFMA(wL1[2], xt, aA);                                           \
        f32x4 aB = MFMA(wL1[3], xs0, zz); aB = MFMA(wL1[4], xs1, aB);        \
        aB = MFMA(wL1[5], xt, aB);                                           \
        short8 xhm; RELU_PACK(aA, aB, xhm);                                  \
        *(short8*)(&XHs[w][lane][0]) = xhm;                                  \
        __syncthreads();                                                     \
        /* ---- P2: L2 (h -> g), tiles 2w, 2w+1 ---- */                      \
        short8 xh0 = *(const short8*)(&XHs[0][lane][0]);                     \
        short8 xh1 = *(const short8*)(&XHs[1][lane][0]);                     \
        short8 xh2 = *(const short8*)(&XHs[2][lane][0]);                     \
        short8 xh3 = *(const short8*)(&XHs[3][lane][0]);                     \
        f32x4 gA = MFMA(wL2[0], xh0, bL2v[0]); gA = MFMA(wL2[1], xh1, gA);   \
        gA = MFMA(wL2[2], xh2, gA);            gA = MFMA(wL2[3], xh3, gA);   \
        f32x4 gB = MFMA(wL2[4], xh0, bL2v[1]); gB = MFMA(wL2[5], xh1, gB);   \
        gB = MFMA(wL2[6], xh2, gB);            gB = MFMA(wL2[7], xh3, gB);   \
        short8 xgm; RELU_PACK(gA, gB, xgm);                                  \
        *(short8*)(&XGs[w][lane][0]) = xgm;                                  \
        __syncthreads();                                                     \
        /* ---- P3: L3 (g -> kv), tile w; si = pre + h*kv ---- */            \
        short8 xg0 = *(const short8*)(&XGs[0][lane][0]);                     \
        short8 xg1 = *(const short8*)(&XGs[1][lane][0]);                     \
        short8 xg2 = *(const short8*)(&XGs[2][lane][0]);                     \
        short8 xg3 = *(const short8*)(&XGs[3][lane][0]);                     \
        kv = MFMA(wL3[0], xg0, bL3v); kv = MFMA(wL3[1], xg1, kv);            \
        kv = MFMA(wL3[2], xg2, kv);   kv = MFMA(wL3[3], xg3, kv);            \
        _Pragma("unroll")                                                    \
        for (int r_ = 0; r_ < 4; ++r_) si[r_] = pre[r_] + (HS) * kv[r_];     \
        *(ushort4v*)(&XSs[w >> 1][lane][4 * (w & 1)]) =                      \
            __builtin_bit_cast(ushort4v, pack4(si));                        \
        __syncthreads();                                                     \
    }

// 8 waves per block = TWO independent 16-row systems (waves 0-3 -> sys A,
// waves 4-7 -> sys B). Each SIMD hosts one A-wave and one B-wave: the HW
// scheduler interleaves them cycle-by-cycle (m114: time ~ max, not sum), so
// B's ds_reads+MFMA chains fill A's ~120cyc load stalls and vice versa —
// the TLP fix for R8's same-wave-ILP regression (compiler serialized A+B in
// one instruction stream). Per-wave code/registers identical to R7 (96 VGPR).
extern "C" __global__ void __launch_bounds__(512, 1)
node_solve(const float* __restrict__ y0, const float* __restrict__ ts,
           const float* __restrict__ gw0, const float* __restrict__ gb0,
           const float* __restrict__ gw1, const float* __restrict__ gb1,
           const float* __restrict__ gw2, const float* __restrict__ gb2,
           float* __restrict__ out)
{
    __shared__ __align__(16) unsigned short XS[2][2][64][8];  // [sys] stage-input
    __shared__ __align__(16) unsigned short XH[2][4][64][8];  // [sys] L1 out
    __shared__ __align__(16) unsigned short XG[2][4][64][8];  // [sys] L2 out

    const int tid  = threadIdx.x;
    const int w8   = tid >> 6;        // wave 0..7
    const int sys  = w8 >> 2;         // system 0/1
    const int w    = w8 & 3;          // role within system 0..3
    const int lane = tid & 63;
    const int q    = lane >> 4;
    const int c    = lane & 15;
    const int row0 = (blockIdx.x << 5) + (sys << 4);   // 32 rows/block

    unsigned short (*XSs)[64][8] = XS[sys];
    unsigned short (*XHs)[64][8] = XH[sys];
    unsigned short (*XGs)[64][8] = XG[sys];

    // ---- weights -> K-permuted register A-frags (this wave's tiles only) ----
    // perm: k-position (ks, q, j) <- source column 32ks+16*(j>>2)+4q+(j&3)
    short8 wL1[6];   // tiles 2w,2w+1 x slices {y0-31, y32-63, [t,bias]}
    short8 wL2[8];   // tiles 2w,2w+1 x 4 k-slices
    short8 wL3[4];   // tile w x 4 k-slices
    f32x4  bL2v[2], bL3v;

    #pragma unroll
    for (int p = 0; p < 2; ++p) {
        const int t = 2 * w + p;
        const int n = 16 * t + c;
        const float* w0r = gw0 + n * 65 + 1;      // col 0 of gw0 is the t-weight
        #pragma unroll
        for (int ks = 0; ks < 2; ++ks) {
            bf16x8 v;
            #pragma unroll
            for (int j = 0; j < 8; ++j)
                v[j] = (__bf16)w0r[32*ks + 16*(j>>2) + 4*q + (j&3)];
            wL1[3*p + ks] = as_s8(v);
        }
        {
            bf16x8 v;
            #pragma unroll
            for (int j = 0; j < 8; ++j) v[j] = (__bf16)0.f;
            if (q == 0) { v[0] = (__bf16)gw0[n*65]; v[1] = (__bf16)gb0[n]; }
            wL1[3*p + 2] = as_s8(v);
        }
        const float* w1r = gw1 + n * 128;
        #pragma unroll
        for (int ks = 0; ks < 4; ++ks) {
            bf16x8 v;
            #pragma unroll
            for (int j = 0; j < 8; ++j)
                v[j] = (__bf16)w1r[32*ks + 16*(j>>2) + 4*q + (j&3)];
            wL2[4*p + ks] = as_s8(v);
        }
        bL2v[p] = *(const f32x4*)(gb1 + 16*t + 4*q);
    }
    {
        const int n = 16 * w + c;
        const float* w2r = gw2 + n * 128;
        #pragma unroll
        for (int ks = 0; ks < 4; ++ks) {
            bf16x8 v;
            #pragma unroll
            for (int j = 0; j < 8; ++j)
                v[j] = (__bf16)w2r[32*ks + 16*(j>>2) + 4*q + (j&3)];
            wL3[ks] = as_s8(v);
        }
        bL3v = *(const f32x4*)(gb2 + 16*w + 4*q);
    }

    // ---- ODE state: this wave owns dims 16w+4q+r of batch row row0+c ----
    f32x4 yn = *(const f32x4*)(y0 + (size_t)(row0 + c) * 64 + 16*w + 4*q);

    const float ts0 = ts[0];
    const float dtv = ts[1] - ts[0];

    // dt-scaled Tsit5: e = dt*b, h_s = dt*a_{s+1,s}, g_sj = dt*(a_sj - b_j)
    const float e1 = dtv * 0.09646076681806523f, e2 = dtv * 0.01f;
    const float e3 = dtv * 0.4798896504144996f,  e4 = dtv * 1.379008574103742f;
    const float e5 = dtv * -3.290069515436081f,  e6 = dtv * 2.324710524099774f;
    const float h0 = dtv * 0.161f;
    const float h1 = dtv * 0.335480655492357f;
    const float h2 = dtv * 4.3622954328695815f;
    const float h3 = dtv * -0.09249506636175525f;
    const float h4 = dtv * -0.028269050394068383f;
    const float g31 = dtv * (-0.008480655492356989f - 0.09646076681806523f);
    const float g41 = dtv * (2.8971530571054935f    - 0.09646076681806523f);
    const float g42 = dtv * (-6.359448489975075f    - 0.01f);
    const float g51 = dtv * (5.325864828439257f     - 0.09646076681806523f);
    const float g52 = dtv * (-11.748883564062828f   - 0.01f);
    const float g53 = dtv * (7.4955393428898365f    - 0.4798896504144996f);
    const float g61 = dtv * (5.86145544294642f      - 0.09646076681806523f);
    const float g62 = dtv * (-12.92096931784711f    - 0.01f);
    const float g63 = dtv * (8.159367898576159f     - 0.4798896504144996f);
    const float g64 = dtv * (-0.071584973281401f    - 1.379008574103742f);

    // ---- initial stage input si1 = y0 -> XS; pre for si2 = y0 ----
    *(ushort4v*)(&XSs[w >> 1][lane][4 * (w & 1)]) =
        __builtin_bit_cast(ushort4v, pack4(yn));
    f32x4 pre = yn, si, kv;
    __syncthreads();

    #pragma unroll 1
    for (int step = 0; step < NSTEPS; ++step) {
        const float t0s = ts0 + (float)step * dtv;
        bf16x4 kb0, kb1, kb2, kb3;

        // ---- stage 1 ----  (tail after barrier: register-only, overlaps P1)
        STAGE(t0s, h0)
        #pragma unroll
        for (int r = 0; r < 4; ++r) yn[r] += e1 * kv[r];
        kb0 = pack4(kv);
        #pragma unroll
        for (int r = 0; r < 4; ++r) pre[r] = yn[r] + g31 * (float)kb0[r];

        // ---- stage 2 ----
        STAGE(t0s + 0.161f * dtv, h1)
        #pragma unroll
        for (int r = 0; r < 4; ++r) yn[r] += e2 * kv[r];
        kb1 = pack4(kv);
        #pragma unroll
        for (int r = 0; r < 4; ++r)
            pre[r] = yn[r] + g41 * (float)kb0[r] + g42 * (float)kb1[r];

        // ---- stage 3 ----
        STAGE(t0s + 0.327f * dtv, h2)
        #pragma unroll
        for (int r = 0; r < 4; ++r) yn[r] += e3 * kv[r];
        kb2 = pack4(kv);
        #pragma unroll
        for (int r = 0; r < 4; ++r)
            pre[r] = yn[r] + g51 * (float)kb0[r] + g52 * (float)kb1[r]
                   + g53 * (float)kb2[r];

        // ---- stage 4 ----
        STAGE(t0s + 0.9f * dtv, h3)
        #pragma unroll
        for (int r = 0; r < 4; ++r) yn[r] += e4 * kv[r];
        kb3 = pack4(kv);
        #pragma unroll
        for (int r = 0; r < 4; ++r)
            pre[r] = yn[r] + g61 * (float)kb0[r] + g62 * (float)kb1[r]
                   + g63 * (float)kb2[r] + g64 * (float)kb3[r];

        // ---- stage 5 ----
        STAGE(t0s + 0.9800255409045097f * dtv, h4)
        #pragma unroll
        for (int r = 0; r < 4; ++r) { yn[r] += e5 * kv[r]; pre[r] = yn[r]; }

        // ---- stage 6: si = yn + e6*kv = new y (exact f32 carry) ----
        STAGE(t0s + dtv, e6)
        #pragma unroll
        for (int r = 0; r < 4; ++r) { yn[r] = si[r]; pre[r] = si[r]; }
    }

    // ---- output: this wave's dims of row row0+c ----
    *(f32x4*)(&out[(size_t)(row0 + c) * 64 + 16*w + 4*q]) = yn;
}

extern "C" void kernel_launch(void* const* d_in, const int* in_sizes, int n_in,
                              void* d_out, int out_size, void* d_ws, size_t ws_size,
                              hipStream_t stream) {
    const float* y0 = (const float*)d_in[0];
    const float* ts = (const float*)d_in[1];
    const float* w0 = (const float*)d_in[2];
    const float* b0 = (const float*)d_in[3];
    const float* w1 = (const float*)d_in[4];
    const float* b1 = (const float*)d_in[5];
    const float* w2 = (const float*)d_in[6];
    const float* b2 = (const float*)d_in[7];
    float* out = (float*)d_out;

    node_solve<<<dim3(64), dim3(512), 0, stream>>>(y0, ts, w0, b0, w1, b1, w2, b2, out);
}

// Round 10
// 277.403 us; speedup vs baseline: 1.2456x; 1.0239x over previous
//
#include <hip/hip_runtime.h>

typedef __attribute__((ext_vector_type(8))) short   short8;
typedef __attribute__((ext_vector_type(8))) __bf16  bf16x8;
typedef __attribute__((ext_vector_type(4))) float   f32x4;

#define NSTEPS 49

static __device__ __forceinline__ short8 as_s8(bf16x8 v) {
    return __builtin_bit_cast(short8, v);
}

#define MFMA(A, B, C) __builtin_amdgcn_mfma_f32_16x16x32_bf16((A), (B), (C), 0, 0, 0)

// xs slices from f32x4 SRC[4] (tile-major state, dims 16t+4q+r):
// slice0[j] = SRC[j>>2][j&3], slice1[j] = SRC[(j>>2)+2][j&3] — in-lane only.
#define BUILD_XS(SRC)                                                        \
    {                                                                        \
        bf16x8 v0_, v1_;                                                     \
        _Pragma("unroll")                                                    \
        for (int j_ = 0; j_ < 8; ++j_) {                                     \
            v0_[j_] = (__bf16)(SRC)[j_ >> 2][j_ & 3];                        \
            v1_[j_] = (__bf16)(SRC)[(j_ >> 2) + 2][j_ & 3];                  \
        }                                                                    \
        xs0 = as_s8(v0_); xs1 = as_s8(v1_);                                  \
    }

// Third L1 K-slice: slot (q=0,j=0) carries t, (q=0,j=1) carries 1.0 (bias col).
#define BUILD_XT(TV)                                                         \
    {                                                                        \
        bf16x8 v_;                                                           \
        _Pragma("unroll") for (int j_ = 0; j_ < 8; ++j_) v_[j_] = (__bf16)0.f; \
        if (q == 0) { v_[0] = (__bf16)(TV); v_[1] = (__bf16)1.0f; }          \
        xt = as_s8(v_);                                                      \
    }

// Pack fresh f32 kv (f32x4[4]) as bf16 history in xs-slice order (8 VGPRs).
#define STORE_KB(KB, KV)                                                     \
    {                                                                        \
        bf16x8 t0_, t1_;                                                     \
        _Pragma("unroll")                                                    \
        for (int j_ = 0; j_ < 8; ++j_) {                                     \
            t0_[j_] = (__bf16)(KV)[j_ >> 2][j_ & 3];                         \
            t1_[j_] = (__bf16)(KV)[(j_ >> 2) + 2][j_ & 3];                   \
        }                                                                    \
        (KB)[0] = t0_; (KB)[1] = t1_;                                        \
    }
#define KF(KB, V) ((float)(KB)[(V) >> 3][(V) & 7])

#define RELU_PACK(AA, AB, OUT)                                               \
    {                                                                        \
        bf16x8 v_;                                                           \
        v_[0]=(__bf16)fmaxf((AA)[0],0.f); v_[1]=(__bf16)fmaxf((AA)[1],0.f);  \
        v_[2]=(__bf16)fmaxf((AA)[2],0.f); v_[3]=(__bf16)fmaxf((AA)[3],0.f);  \
        v_[4]=(__bf16)fmaxf((AB)[0],0.f); v_[5]=(__bf16)fmaxf((AB)[1],0.f);  \
        v_[6]=(__bf16)fmaxf((AB)[2],0.f); v_[7]=(__bf16)fmaxf((AB)[3],0.f);  \
        OUT = as_s8(v_);                                                     \
    }

// One Tsit5 stage, 2 barriers (R7 had 3). L1/L2 tile-split across 4 waves;
// L3 computed REDUNDANTLY by every wave (all 16 wL3 frags): after the g-read
// each wave owns the full kv (16 dims/lane over 4 tiles), so the state update
// and the next stage's xs B-frags are built entirely in registers — the
// si-exchange barrier and L1's xs ds_reads are deleted from the chain.
#define STAGE(TN, HS)                                                        \
    {                                                                        \
        const f32x4 zz = {0.f, 0.f, 0.f, 0.f};                               \
        short8 xt; BUILD_XT(TN);                                             \
        /* ---- P1: L1 own tiles 2w,2w+1 (xs in registers) ---- */           \
        f32x4 aA = MFMA(wL1[0], xs0, zz); aA = MFMA(wL1[1], xs1, aA);        \
        aA = MFMA(wL1[2], xt, aA);                                           \
        f32x4 aB = MFMA(wL1[3], xs0, zz); aB = MFMA(wL1[4], xs1, aB);        \
        aB = MFMA(wL1[5], xt, aB);                                           \
        short8 xhm; RELU_PACK(aA, aB, xhm);                                  \
        *(short8*)(&XH[w][lane][0]) = xhm;                                   \
        __syncthreads();                                                     \
        /* ---- P2: L2 own tiles ---- */                                     \
        short8 xh0 = *(const short8*)(&XH[0][lane][0]);                      \
        short8 xh1 = *(const short8*)(&XH[1][lane][0]);                      \
        short8 xh2 = *(const short8*)(&XH[2][lane][0]);                      \
        short8 xh3 = *(const short8*)(&XH[3][lane][0]);                      \
        f32x4 gA = MFMA(wL2[0], xh0, bL2v[0]); gA = MFMA(wL2[1], xh1, gA);   \
        gA = MFMA(wL2[2], xh2, gA);            gA = MFMA(wL2[3], xh3, gA);   \
        f32x4 gB = MFMA(wL2[4], xh0, bL2v[1]); gB = MFMA(wL2[5], xh1, gB);   \
        gB = MFMA(wL2[6], xh2, gB);            gB = MFMA(wL2[7], xh3, gB);   \
        short8 xgm; RELU_PACK(gA, gB, xgm);                                  \
        *(short8*)(&XG[w][lane][0]) = xgm;                                   \
        __syncthreads();                                                     \
        /* ---- P3: L3 ALL tiles (redundant per wave) ---- */                \
        short8 xg0 = *(const short8*)(&XG[0][lane][0]);                      \
        short8 xg1 = *(const short8*)(&XG[1][lane][0]);                      \
        short8 xg2 = *(const short8*)(&XG[2][lane][0]);                      \
        short8 xg3 = *(const short8*)(&XG[3][lane][0]);                      \
        _Pragma("unroll")                                                    \
        for (int t_ = 0; t_ < 4; ++t_) {                                     \
            f32x4 ac_ = MFMA(wL3[4*t_ + 0], xg0, bL3v[t_]);                  \
            ac_ = MFMA(wL3[4*t_ + 1], xg1, ac_);                             \
            ac_ = MFMA(wL3[4*t_ + 2], xg2, ac_);                             \
            ac_ = MFMA(wL3[4*t_ + 3], xg3, ac_);                             \
            kv[t_] = ac_;                                                    \
        }                                                                    \
        f32x4 si_[4];                                                        \
        _Pragma("unroll")                                                    \
        for (int t_ = 0; t_ < 4; ++t_) si_[t_] = pre[t_] + (HS) * kv[t_];    \
        BUILD_XS(si_);                                                       \
        lastsi0 = si_[0]; lastsi1 = si_[1];                                  \
        lastsi2 = si_[2]; lastsi3 = si_[3];                                  \
    }

// 128 blocks x 4 waves; each block owns one 16-row system (max batch
// parallelism: 2048/16 = 128 independent chains). Wave w holds L1 tiles
// 2w,2w+1 (24 VGPR), L2 tiles 2w,2w+1 (32), ALL of L3 (64) + redundant
// full per-lane state (16 dims: tiles 0-3 x 4q+r). 2 barriers/stage.
extern "C" __global__ void __launch_bounds__(256, 1)
node_solve(const float* __restrict__ y0, const float* __restrict__ ts,
           const float* __restrict__ gw0, const float* __restrict__ gb0,
           const float* __restrict__ gw1, const float* __restrict__ gb1,
           const float* __restrict__ gw2, const float* __restrict__ gb2,
           float* __restrict__ out)
{
    __shared__ __align__(16) unsigned short XH[4][64][8];  // L1 out slices
    __shared__ __align__(16) unsigned short XG[4][64][8];  // L2 out slices

    const int tid  = threadIdx.x;
    const int w    = tid >> 6;      // wave 0..3
    const int lane = tid & 63;
    const int q    = lane >> 4;
    const int c    = lane & 15;
    const int row0 = blockIdx.x << 4;

    // ---- weights -> K-permuted register A-frags ----
    // perm: k-position (ks, q, j) <- source column 32ks+16*(j>>2)+4q+(j&3)
    short8 wL1[6];    // own tiles 2w,2w+1 x {y0-31, y32-63, [t,bias]}
    short8 wL2[8];    // own tiles 2w,2w+1 x 4 k-slices
    short8 wL3[16];   // ALL 4 tiles x 4 k-slices (redundant)
    f32x4  bL2v[2], bL3v[4];

    #pragma unroll
    for (int p = 0; p < 2; ++p) {
        const int t = 2 * w + p;
        const int n = 16 * t + c;
        const float* w0r = gw0 + n * 65 + 1;      // col 0 of gw0 is the t-weight
        #pragma unroll
        for (int ks = 0; ks < 2; ++ks) {
            bf16x8 v;
            #pragma unroll
            for (int j = 0; j < 8; ++j)
                v[j] = (__bf16)w0r[32*ks + 16*(j>>2) + 4*q + (j&3)];
            wL1[3*p + ks] = as_s8(v);
        }
        {
            bf16x8 v;
            #pragma unroll
            for (int j = 0; j < 8; ++j) v[j] = (__bf16)0.f;
            if (q == 0) { v[0] = (__bf16)gw0[n*65]; v[1] = (__bf16)gb0[n]; }
            wL1[3*p + 2] = as_s8(v);
        }
        const float* w1r = gw1 + n * 128;
        #pragma unroll
        for (int ks = 0; ks < 4; ++ks) {
            bf16x8 v;
            #pragma unroll
            for (int j = 0; j < 8; ++j)
                v[j] = (__bf16)w1r[32*ks + 16*(j>>2) + 4*q + (j&3)];
            wL2[4*p + ks] = as_s8(v);
        }
        bL2v[p] = *(const f32x4*)(gb1 + 16*t + 4*q);
    }
    #pragma unroll
    for (int t = 0; t < 4; ++t) {
        const int n = 16 * t + c;
        const float* w2r = gw2 + n * 128;
        #pragma unroll
        for (int ks = 0; ks < 4; ++ks) {
            bf16x8 v;
            #pragma unroll
            for (int j = 0; j < 8; ++j)
                v[j] = (__bf16)w2r[32*ks + 16*(j>>2) + 4*q + (j&3)];
            wL3[4*t + ks] = as_s8(v);
        }
        bL3v[t] = *(const f32x4*)(gb2 + 16*t + 4*q);
    }

    // ---- state: lane holds dims {16t+4q+r} of row row0+c (redundant/wave) ----
    f32x4 yn[4];
    #pragma unroll
    for (int t = 0; t < 4; ++t)
        yn[t] = *(const f32x4*)(y0 + (size_t)(row0 + c) * 64 + 16*t + 4*q);

    const float ts0 = ts[0];
    const float dtv = ts[1] - ts[0];

    // dt-scaled Tsit5: e = dt*b, h_s = dt*a_{s+1,s}, g_sj = dt*(a_sj - b_j)
    const float e1 = dtv * 0.09646076681806523f, e2 = dtv * 0.01f;
    const float e3 = dtv * 0.4798896504144996f,  e4 = dtv * 1.379008574103742f;
    const float e5 = dtv * -3.290069515436081f,  e6 = dtv * 2.324710524099774f;
    const float h0 = dtv * 0.161f;
    const float h1 = dtv * 0.335480655492357f;
    const float h2 = dtv * 4.3622954328695815f;
    const float h3 = dtv * -0.09249506636175525f;
    const float h4 = dtv * -0.028269050394068383f;
    const float g31 = dtv * (-0.008480655492356989f - 0.09646076681806523f);
    const float g41 = dtv * (2.8971530571054935f    - 0.09646076681806523f);
    const float g42 = dtv * (-6.359448489975075f    - 0.01f);
    const float g51 = dtv * (5.325864828439257f     - 0.09646076681806523f);
    const float g52 = dtv * (-11.748883564062828f   - 0.01f);
    const float g53 = dtv * (7.4955393428898365f    - 0.4798896504144996f);
    const float g61 = dtv * (5.86145544294642f      - 0.09646076681806523f);
    const float g62 = dtv * (-12.92096931784711f    - 0.01f);
    const float g63 = dtv * (8.159367898576159f     - 0.4798896504144996f);
    const float g64 = dtv * (-0.071584973281401f    - 1.379008574103742f);

    short8 xs0, xs1;
    f32x4  pre[4], kv[4];
    f32x4  lastsi0, lastsi1, lastsi2, lastsi3;

    // initial: si1 = y0 (in registers), pre for si2 = y0
    BUILD_XS(yn);
    #pragma unroll
    for (int t = 0; t < 4; ++t) pre[t] = yn[t];

    #pragma unroll 1
    for (int step = 0; step < NSTEPS; ++step) {
        const float t0s = ts0 + (float)step * dtv;
        bf16x8 kb0[2], kb1[2], kb2[2], kb3[2];

        // ---- stage 1 ---- (state tail: register-only)
        STAGE(t0s, h0)
        #pragma unroll
        for (int t = 0; t < 4; ++t) yn[t] += e1 * kv[t];
        STORE_KB(kb0, kv);
        #pragma unroll
        for (int v = 0; v < 16; ++v)
            pre[v>>2][v&3] = yn[v>>2][v&3] + g31 * KF(kb0, v);

        // ---- stage 2 ----
        STAGE(t0s + 0.161f * dtv, h1)
        #pragma unroll
        for (int t = 0; t < 4; ++t) yn[t] += e2 * kv[t];
        STORE_KB(kb1, kv);
        #pragma unroll
        for (int v = 0; v < 16; ++v)
            pre[v>>2][v&3] = yn[v>>2][v&3] + g41*KF(kb0,v) + g42*KF(kb1,v);

        // ---- stage 3 ----
        STAGE(t0s + 0.327f * dtv, h2)
        #pragma unroll
        for (int t = 0; t < 4; ++t) yn[t] += e3 * kv[t];
        STORE_KB(kb2, kv);
        #pragma unroll
        for (int v = 0; v < 16; ++v)
            pre[v>>2][v&3] = yn[v>>2][v&3] + g51*KF(kb0,v) + g52*KF(kb1,v)
                           + g53*KF(kb2,v);

        // ---- stage 4 ----
        STAGE(t0s + 0.9f * dtv, h3)
        #pragma unroll
        for (int t = 0; t < 4; ++t) yn[t] += e4 * kv[t];
        STORE_KB(kb3, kv);
        #pragma unroll
        for (int v = 0; v < 16; ++v)
            pre[v>>2][v&3] = yn[v>>2][v&3] + g61*KF(kb0,v) + g62*KF(kb1,v)
                           + g63*KF(kb2,v) + g64*KF(kb3,v);

        // ---- stage 5 ----
        STAGE(t0s + 0.9800255409045097f * dtv, h4)
        #pragma unroll
        for (int t = 0; t < 4; ++t) { yn[t] += e5 * kv[t]; pre[t] = yn[t]; }

        // ---- stage 6: si = yn + e6*kv = new y (exact f32 carry) ----
        STAGE(t0s + dtv, e6)
        yn[0] = lastsi0; yn[1] = lastsi1; yn[2] = lastsi2; yn[3] = lastsi3;
        #pragma unroll
        for (int t = 0; t < 4; ++t) pre[t] = yn[t];
    }

    // ---- output: wave w writes its tile (state is wave-redundant) ----
    *(f32x4*)(&out[(size_t)(row0 + c) * 64 + 16*w + 4*q]) = yn[w];
}

extern "C" void kernel_launch(void* const* d_in, const int* in_sizes, int n_in,
                              void* d_out, int out_size, void* d_ws, size_t ws_size,
                              hipStream_t stream) {
    const float* y0 = (const float*)d_in[0];
    const float* ts = (const float*)d_in[1];
    const float* w0 = (const float*)d_in[2];
    const float* b0 = (const float*)d_in[3];
    const float* w1 = (const float*)d_in[4];
    const float* b1 = (const float*)d_in[5];
    const float* w2 = (const float*)d_in[6];
    const float* b2 = (const float*)d_in[7];
    float* out = (float*)d_out;

    node_solve<<<dim3(128), dim3(256), 0, stream>>>(y0, ts, w0, b0, w1, b1, w2, b2, out);
}